// Round 6
// baseline (391.864 us; speedup 1.0000x reference)
//
#include <hip/hip_runtime.h>

// sigmoid( (1/L) * sum_{l<len_b} dot(emb_table[tokens[b,l]], W) + bias )
// HBM-bound gather: ~sum(lengths)*4000B ~= 262 MB of row reads.
// v6 = v5 (seq-major, 4x oversubscribe) + fused per-seq last-arrival finalize:
//   each block writes partial -> fence -> atomicAdd(cnt[seq]); the 128th block
//   reduces that seq's partials in fixed order (bit-deterministic) + sigmoid.
//   Counters re-zeroed each call by a 256B memset node (poison/replay-proof).

constexpr int B_ = 64;
constexpr int L_ = 2048;
constexpr int P_ = 1000;           // floats per row (250 float4, rows 16B-aligned)
constexpr int CPS = 128;           // chunks (blocks) per sequence
constexpr int BDIM = 256;          // 4 waves
constexpr int WAVES = BDIM / 64;
constexpr int NBLK = B_ * CPS;     // 8192 blocks

__global__ __launch_bounds__(BDIM) void pool_dot_kernel(
    const int* __restrict__ tokens,    // [B_, L_]
    const int* __restrict__ lengths,   // [B_]
    const float* __restrict__ emb,     // [VOCAB, P_]
    const float* __restrict__ W,       // [P_]
    const float* __restrict__ bias,    // [1]
    float* __restrict__ out,           // [B_]
    float* __restrict__ partial,       // [NBLK], partial[seq*CPS + chunk]
    int* __restrict__ cnt)             // [B_], zeroed by memset node each call
{
    const int blk   = blockIdx.x;
    const int seq   = blk >> 7;        // seq-major: co-resident blocks share seq
    const int chunk = blk & (CPS - 1);
    const int lane  = threadIdx.x & 63;
    const int wave  = threadIdx.x >> 6;

    const int len = (int)lengths[seq];
    __shared__ float red[WAVES];
    __shared__ int last_flag;

    float accl = 0.0f;
    const int s0 = chunk + CPS * wave;                            // [0, 512)
    const int nm = (s0 < len) ? (((len - 1 - s0) >> 9) + 1) : 0;  // stride 512, <=4

    if (nm > 0) {
        // W fragment in registers: lane covers float4 indices lane + 64k, k=0..3
        const float4* W4 = (const float4*)W;
        float4 wf[4];
        #pragma unroll
        for (int k = 0; k < 4; ++k) {
            const int j = lane + 64 * k;
            if (j < P_ / 4) wf[k] = W4[j];
            else            wf[k] = make_float4(0.f, 0.f, 0.f, 0.f);
        }
        const int* trow = tokens + seq * L_;
        #pragma unroll 4
        for (int m = 0; m < nm; ++m) {
            const int t   = s0 + (m << 9);
            const int row = trow[t];                       // wave-uniform load
            const float4* e4 = (const float4*)(emb + (size_t)row * P_);
            #pragma unroll
            for (int k = 0; k < 4; ++k) {
                const int j = lane + 64 * k;
                if (j < P_ / 4) {
                    const float4 e = e4[j];
                    accl = fmaf(e.x, wf[k].x, accl);
                    accl = fmaf(e.y, wf[k].y, accl);
                    accl = fmaf(e.z, wf[k].z, accl);
                    accl = fmaf(e.w, wf[k].w, accl);
                }
            }
        }
    }

    // wave reduction (64 lanes)
    #pragma unroll
    for (int off = 32; off > 0; off >>= 1)
        accl += __shfl_down(accl, off, 64);
    if (lane == 0) red[wave] = accl;
    __syncthreads();
    if (threadIdx.x == 0) {
        float s = 0.0f;
        #pragma unroll
        for (int w = 0; w < WAVES; ++w) s += red[w];
        partial[blk] = s;
        __threadfence();                               // publish partial
        const int old = atomicAdd(&cnt[seq], 1);       // device-scope
        last_flag = (old == CPS - 1) ? 1 : 0;
    }
    __syncthreads();

    if (last_flag) {
        // This block is the 128th arrival for `seq`: all partials published.
        __threadfence();                               // acquire
        const int i = threadIdx.x;
        float v = (i < CPS) ? partial[seq * CPS + i] : 0.0f;
        #pragma unroll
        for (int off = 32; off > 0; off >>= 1)
            v += __shfl_down(v, off, 64);
        if (lane == 0) red[wave] = v;
        __syncthreads();
        if (threadIdx.x == 0) {
            const float t = red[0] + red[1] + red[2] + red[3];
            const float z = t * (1.0f / (float)L_) + bias[0];
            out[seq] = 1.0f / (1.0f + expf(-z));
        }
    }
}

extern "C" void kernel_launch(void* const* d_in, const int* in_sizes, int n_in,
                              void* d_out, int out_size, void* d_ws, size_t ws_size,
                              hipStream_t stream) {
    const int*   tokens  = (const int*)d_in[0];
    const int*   lengths = (const int*)d_in[1];
    const float* emb     = (const float*)d_in[2];
    const float* W       = (const float*)d_in[3];
    const float* bias    = (const float*)d_in[4];
    float* out = (float*)d_out;

    int*   cnt     = (int*)d_ws;                        // 64 ints (256 B)
    float* partial = (float*)((char*)d_ws + 256);       // NBLK floats (32 KB)

    hipMemsetAsync(cnt, 0, B_ * sizeof(int), stream);   // memset node: replay-safe
    pool_dot_kernel<<<NBLK, BDIM, 0, stream>>>(tokens, lengths, emb, W, bias,
                                               out, partial, cnt);
}

// Round 7
// 87.050 us; speedup vs baseline: 4.5016x; 4.5016x over previous
//
#include <hip/hip_runtime.h>

// sigmoid( (1/L) * sum_{l<len_b} dot(emb_table[tokens[b,l]], W) + bias )
// HBM/L3-bound gather: ~sum(lengths)*4000B ~= 262 MB of row reads.
// v7 = v5 (seq-major, 4x oversubscribe) + FENCELESS fused last-arrival
// finalize: partial published via agent-scope (sc0 sc1) relaxed atomic store
// + s_waitcnt vmcnt(0) ordering + relaxed agent atomicAdd counter. No
// __threadfence() (v6 showed a per-block device fence = L2 flush = 10x blowup).

constexpr int B_ = 64;
constexpr int L_ = 2048;
constexpr int P_ = 1000;           // floats per row (250 float4, rows 16B-aligned)
constexpr int CPS = 128;           // chunks (blocks) per sequence
constexpr int BDIM = 256;          // 4 waves
constexpr int WAVES = BDIM / 64;
constexpr int NBLK = B_ * CPS;     // 8192 blocks

__global__ __launch_bounds__(BDIM) void pool_dot_kernel(
    const int* __restrict__ tokens,    // [B_, L_]
    const int* __restrict__ lengths,   // [B_]
    const float* __restrict__ emb,     // [VOCAB, P_]
    const float* __restrict__ W,       // [P_]
    const float* __restrict__ bias,    // [1]
    float* __restrict__ out,           // [B_]
    float* __restrict__ partial,       // [NBLK], partial[seq*CPS + chunk]
    int* __restrict__ cnt)             // [B_], zeroed by memset node each call
{
    const int blk   = blockIdx.x;
    const int seq   = blk >> 7;        // seq-major: co-resident blocks share seq
    const int chunk = blk & (CPS - 1);
    const int lane  = threadIdx.x & 63;
    const int wave  = threadIdx.x >> 6;

    const int len = (int)lengths[seq];
    __shared__ float red[WAVES];
    __shared__ int last_flag;

    float accl = 0.0f;
    const int s0 = chunk + CPS * wave;                            // [0, 512)
    const int nm = (s0 < len) ? (((len - 1 - s0) >> 9) + 1) : 0;  // stride 512, <=4

    if (nm > 0) {
        // W fragment in registers: lane covers float4 indices lane + 64k, k=0..3
        const float4* W4 = (const float4*)W;
        float4 wf[4];
        #pragma unroll
        for (int k = 0; k < 4; ++k) {
            const int j = lane + 64 * k;
            if (j < P_ / 4) wf[k] = W4[j];
            else            wf[k] = make_float4(0.f, 0.f, 0.f, 0.f);
        }
        const int* trow = tokens + seq * L_;
        #pragma unroll 4
        for (int m = 0; m < nm; ++m) {
            const int t   = s0 + (m << 9);
            const int row = trow[t];                       // wave-uniform load
            const float4* e4 = (const float4*)(emb + (size_t)row * P_);
            #pragma unroll
            for (int k = 0; k < 4; ++k) {
                const int j = lane + 64 * k;
                if (j < P_ / 4) {
                    const float4 e = e4[j];
                    accl = fmaf(e.x, wf[k].x, accl);
                    accl = fmaf(e.y, wf[k].y, accl);
                    accl = fmaf(e.z, wf[k].z, accl);
                    accl = fmaf(e.w, wf[k].w, accl);
                }
            }
        }
    }

    // wave reduction (64 lanes)
    #pragma unroll
    for (int off = 32; off > 0; off >>= 1)
        accl += __shfl_down(accl, off, 64);
    if (lane == 0) red[wave] = accl;
    __syncthreads();
    if (threadIdx.x == 0) {
        float s = 0.0f;
        #pragma unroll
        for (int w = 0; w < WAVES; ++w) s += red[w];
        // Publish partial at the agent coherence point (sc0 sc1 store),
        // order it before the counter bump with a plain vmcnt wait —
        // NO cache-flushing fence.
        __hip_atomic_store(&partial[blk], s, __ATOMIC_RELAXED,
                           __HIP_MEMORY_SCOPE_AGENT);
        asm volatile("s_waitcnt vmcnt(0)" ::: "memory");
        const int old = __hip_atomic_fetch_add(&cnt[seq], 1, __ATOMIC_RELAXED,
                                               __HIP_MEMORY_SCOPE_AGENT);
        last_flag = (old == CPS - 1) ? 1 : 0;
    }
    __syncthreads();

    if (last_flag) {
        // 128th arrival for `seq`: all partials are at the coherence point.
        // Read them coherently (bypass possibly-stale local L2), fixed order.
        const int i = threadIdx.x;
        float v = 0.0f;
        if (i < CPS)
            v = __hip_atomic_load(&partial[seq * CPS + i], __ATOMIC_RELAXED,
                                  __HIP_MEMORY_SCOPE_AGENT);
        #pragma unroll
        for (int off = 32; off > 0; off >>= 1)
            v += __shfl_down(v, off, 64);
        if (lane == 0) red[wave] = v;
        __syncthreads();
        if (threadIdx.x == 0) {
            const float t = red[0] + red[1] + red[2] + red[3];
            const float z = t * (1.0f / (float)L_) + bias[0];
            out[seq] = 1.0f / (1.0f + expf(-z));
        }
    }
}

extern "C" void kernel_launch(void* const* d_in, const int* in_sizes, int n_in,
                              void* d_out, int out_size, void* d_ws, size_t ws_size,
                              hipStream_t stream) {
    const int*   tokens  = (const int*)d_in[0];
    const int*   lengths = (const int*)d_in[1];
    const float* emb     = (const float*)d_in[2];
    const float* W       = (const float*)d_in[3];
    const float* bias    = (const float*)d_in[4];
    float* out = (float*)d_out;

    int*   cnt     = (int*)d_ws;                        // 64 ints (256 B)
    float* partial = (float*)((char*)d_ws + 256);       // NBLK floats (32 KB)

    hipMemsetAsync(cnt, 0, B_ * sizeof(int), stream);   // memset node: replay-safe
    pool_dot_kernel<<<NBLK, BDIM, 0, stream>>>(tokens, lengths, emb, W, bias,
                                               out, partial, cnt);
}

// Round 8
// 45.630 us; speedup vs baseline: 8.5879x; 1.9077x over previous
//
#include <hip/hip_runtime.h>

// sigmoid( (1/L) * sum_{l<len_b} dot(emb_table[tokens[b,l]], W) + bias )
// HBM/L3-bound gather: ~sum(lengths)*4000B ~= 262 MB of row reads.
// v8 = v5 geometry (seq-major, CPS=128, 2 kernels — fused-finalize abandoned:
// v6 fence = 8.4x, v7 agent-atomics = 1.9x) + forced 16-deep load batch:
// all 4 rows' float4 loads issued before any FMA (sched_barrier pinned).
// Tests the latency/MLP hypothesis vs the service-BW hypothesis.

constexpr int B_ = 64;
constexpr int L_ = 2048;
constexpr int P_ = 1000;           // floats per row (250 float4, rows 16B-aligned)
constexpr int CPS = 128;           // chunks (blocks) per sequence
constexpr int BDIM = 256;          // 4 waves
constexpr int WAVES = BDIM / 64;
constexpr int NBLK = B_ * CPS;     // 8192 blocks

__global__ __launch_bounds__(BDIM) void pool_dot_kernel(
    const int* __restrict__ tokens,    // [B_, L_]
    const int* __restrict__ lengths,   // [B_]
    const float* __restrict__ emb,     // [VOCAB, P_]
    const float* __restrict__ W,       // [P_]
    float* __restrict__ partial)       // [NBLK]
{
    const int blk   = blockIdx.x;
    const int seq   = blk >> 7;        // seq-major: co-resident blocks share seq
    const int chunk = blk & (CPS - 1);
    const int lane  = threadIdx.x & 63;
    const int wave  = threadIdx.x >> 6;

    const int len = (int)lengths[seq];
    __shared__ float red[WAVES];

    float accl = 0.0f;
    const int s0 = chunk + CPS * wave;                            // [0, 512)
    const int nm = (s0 < len) ? (((len - 1 - s0) >> 9) + 1) : 0;  // stride 512, <=4

    if (nm > 0) {
        // W fragment in registers: lane covers float4 indices lane + 64k, k=0..3
        const float4* W4 = (const float4*)W;
        float4 wf[4];
        #pragma unroll
        for (int k = 0; k < 4; ++k) {
            const int j = lane + 64 * k;
            if (j < P_ / 4) wf[k] = W4[j];
            else            wf[k] = make_float4(0.f, 0.f, 0.f, 0.f);
        }

        // All 4 token indices up front (clamped dup for m>=nm: keeps the
        // speculative loads legal + un-DCE-able, they L1-hit row[nm-1]).
        const int* trow = tokens + seq * L_;
        const int nc = nm - 1;
        int rows[4];
        #pragma unroll
        for (int m = 0; m < 4; ++m) {
            const int mm = (m <= nc) ? m : nc;
            rows[m] = trow[s0 + (mm << 9)];
        }

        // Issue ALL 16 float4 loads before any FMA (16 KB/wave in flight).
        float4 e[4][4];
        #pragma unroll
        for (int m = 0; m < 4; ++m) {
            const float4* p = (const float4*)(emb + (size_t)rows[m] * P_);
            #pragma unroll
            for (int k = 0; k < 4; ++k) {
                const int j = lane + 64 * k;
                e[m][k] = (j < P_ / 4) ? p[j] : make_float4(0.f, 0.f, 0.f, 0.f);
            }
        }
        __builtin_amdgcn_sched_barrier(0);   // pin: no FMA hoisted above loads

        #pragma unroll
        for (int m = 0; m < 4; ++m) {
            if (m < nm) {                    // wave-uniform branch
                #pragma unroll
                for (int k = 0; k < 4; ++k) {
                    accl = fmaf(e[m][k].x, wf[k].x, accl);
                    accl = fmaf(e[m][k].y, wf[k].y, accl);
                    accl = fmaf(e[m][k].z, wf[k].z, accl);
                    accl = fmaf(e[m][k].w, wf[k].w, accl);
                }
            }
        }
    }

    // wave reduction (64 lanes)
    #pragma unroll
    for (int off = 32; off > 0; off >>= 1)
        accl += __shfl_down(accl, off, 64);
    if (lane == 0) red[wave] = accl;
    __syncthreads();
    if (threadIdx.x == 0) {
        float s = 0.0f;
        #pragma unroll
        for (int w = 0; w < WAVES; ++w) s += red[w];
        partial[blk] = s;   // every block writes -> no ws zeroing needed
    }
}

// Single block, 256 threads: 4 threads per sequence, each sums 32 partials.
__global__ __launch_bounds__(256) void finalize_kernel(
    const float* __restrict__ partial, // [NBLK] = [B_ * CPS]
    const float* __restrict__ bias,    // [1]
    float* __restrict__ out)           // [B_]
{
    const int i   = threadIdx.x;
    const int seq = i >> 2;
    const int q   = i & 3;
    float s = 0.0f;
    #pragma unroll
    for (int j = 0; j < CPS / 4; ++j)
        s += partial[seq * CPS + q + 4 * j];
    s += __shfl_xor(s, 1, 64);
    s += __shfl_xor(s, 2, 64);
    if (q == 0) {
        const float v = s * (1.0f / (float)L_) + bias[0];
        out[seq] = 1.0f / (1.0f + expf(-v));
    }
}

extern "C" void kernel_launch(void* const* d_in, const int* in_sizes, int n_in,
                              void* d_out, int out_size, void* d_ws, size_t ws_size,
                              hipStream_t stream) {
    const int*   tokens  = (const int*)d_in[0];
    const int*   lengths = (const int*)d_in[1];
    const float* emb     = (const float*)d_in[2];
    const float* W       = (const float*)d_in[3];
    const float* bias    = (const float*)d_in[4];
    float* out     = (float*)d_out;
    float* partial = (float*)d_ws;   // NBLK floats = 32 KB

    pool_dot_kernel<<<NBLK, BDIM, 0, stream>>>(tokens, lengths, emb, W, partial);
    finalize_kernel<<<1, 256, 0, stream>>>(partial, bias, out);
}